// Round 1
// baseline (5475.450 us; speedup 1.0000x reference)
//
#include <hip/hip_runtime.h>
#include <math.h>

#define D_MODEL 512
#define D_INNER 1024
#define L_SEQ 1024
#define BSZ 4
#define NROWS (BSZ * L_SEQ) /* 4096 */
#define DT_RANK 32
#define D_STATE 16

// ---------------------------------------------------------------------------
// LayerNorm: one wave (64 lanes) per row of 512
// ---------------------------------------------------------------------------
__global__ __launch_bounds__(64) void ln_kernel(const float* __restrict__ x,
                                                const float* __restrict__ g,
                                                const float* __restrict__ b,
                                                float* __restrict__ out) {
    int row = blockIdx.x;
    int lane = threadIdx.x;
    const float* xr = x + (size_t)row * D_MODEL;
    float4 v0 = *(const float4*)(xr + lane * 8);
    float4 v1 = *(const float4*)(xr + lane * 8 + 4);
    float s = v0.x + v0.y + v0.z + v0.w + v1.x + v1.y + v1.z + v1.w;
    float ss = v0.x * v0.x + v0.y * v0.y + v0.z * v0.z + v0.w * v0.w +
               v1.x * v1.x + v1.y * v1.y + v1.z * v1.z + v1.w * v1.w;
#pragma unroll
    for (int o = 32; o >= 1; o >>= 1) {
        s += __shfl_xor(s, o);
        ss += __shfl_xor(ss, o);
    }
    float mean = s * (1.f / D_MODEL);
    float var = ss * (1.f / D_MODEL) - mean * mean;
    float rstd = rsqrtf(var + 1e-5f);
    float4 g0 = *(const float4*)(g + lane * 8);
    float4 g1 = *(const float4*)(g + lane * 8 + 4);
    float4 b0 = *(const float4*)(b + lane * 8);
    float4 b1 = *(const float4*)(b + lane * 8 + 4);
    float4 o0, o1;
    o0.x = (v0.x - mean) * rstd * g0.x + b0.x;
    o0.y = (v0.y - mean) * rstd * g0.y + b0.y;
    o0.z = (v0.z - mean) * rstd * g0.z + b0.z;
    o0.w = (v0.w - mean) * rstd * g0.w + b0.w;
    o1.x = (v1.x - mean) * rstd * g1.x + b1.x;
    o1.y = (v1.y - mean) * rstd * g1.y + b1.y;
    o1.z = (v1.z - mean) * rstd * g1.z + b1.z;
    o1.w = (v1.w - mean) * rstd * g1.w + b1.w;
    float* orow = out + (size_t)row * D_MODEL;
    *(float4*)(orow + lane * 8) = o0;
    *(float4*)(orow + lane * 8 + 4) = o1;
}

// ---------------------------------------------------------------------------
// Generic tiled fp32 GEMM: C[m,n] = epi( sum_k A[m,k]*W[n,k] )
// A row stride = lda (for the dtproj case where A is a strided view).
// EPI: 0 none, 1 bias+softplus, 2 +res, 3 bias+gelu, 4 bias+res
// Tile 64x64, BK=32, 256 threads, 4x4 per thread.
// M % 64 == 0, N % 64 == 0, K % 32 == 0 (true for all calls here).
// ---------------------------------------------------------------------------
#define BM 64
#define BN 64
#define BKK 32

template <int EPI>
__device__ inline float apply_epi(float v, const float* __restrict__ bias,
                                  const float* __restrict__ res, size_t off, int n) {
    if (EPI == 1) {
        float t = v + bias[n];
        return (t > 20.f) ? t : log1pf(expf(t));
    } else if (EPI == 2) {
        return v + res[off];
    } else if (EPI == 3) {
        float t = v + bias[n];
        return 0.5f * t * (1.f + erff(t * 0.70710678118654752f));
    } else if (EPI == 4) {
        return v + bias[n] + res[off];
    }
    return v;
}

template <int EPI>
__global__ __launch_bounds__(256) void gemm_kernel(
    const float* __restrict__ A, const float* __restrict__ W,
    const float* __restrict__ bias, const float* __restrict__ res,
    float* __restrict__ C, int M, int N, int K, int lda) {
    __shared__ __align__(16) float As[BKK][BM + 4];
    __shared__ __align__(16) float Ws[BKK][BN + 4];
    int tid = threadIdx.x;
    int m0 = blockIdx.y * BM;
    int n0 = blockIdx.x * BN;
    int ty = tid >> 4;   // 0..15
    int tx = tid & 15;   // 0..15
    float acc[4][4] = {};

    for (int k0 = 0; k0 < K; k0 += BKK) {
#pragma unroll
        for (int i = 0; i < 2; i++) {
            int e = tid + i * 256;       // 0..511 over 64x8 float4 grid
            int row = e >> 3;            // 0..63
            int c4 = (e & 7) * 4;        // 0,4,..,28
            float4 av = *(const float4*)(A + (size_t)(m0 + row) * lda + k0 + c4);
            As[c4 + 0][row] = av.x;
            As[c4 + 1][row] = av.y;
            As[c4 + 2][row] = av.z;
            As[c4 + 3][row] = av.w;
            float4 wv = *(const float4*)(W + (size_t)(n0 + row) * K + k0 + c4);
            Ws[c4 + 0][row] = wv.x;
            Ws[c4 + 1][row] = wv.y;
            Ws[c4 + 2][row] = wv.z;
            Ws[c4 + 3][row] = wv.w;
        }
        __syncthreads();
#pragma unroll
        for (int kk = 0; kk < BKK; kk++) {
            float4 a4 = *(const float4*)&As[kk][ty * 4];
            float4 b4 = *(const float4*)&Ws[kk][tx * 4];
            acc[0][0] += a4.x * b4.x; acc[0][1] += a4.x * b4.y;
            acc[0][2] += a4.x * b4.z; acc[0][3] += a4.x * b4.w;
            acc[1][0] += a4.y * b4.x; acc[1][1] += a4.y * b4.y;
            acc[1][2] += a4.y * b4.z; acc[1][3] += a4.y * b4.w;
            acc[2][0] += a4.z * b4.x; acc[2][1] += a4.z * b4.y;
            acc[2][2] += a4.z * b4.z; acc[2][3] += a4.z * b4.w;
            acc[3][0] += a4.w * b4.x; acc[3][1] += a4.w * b4.y;
            acc[3][2] += a4.w * b4.z; acc[3][3] += a4.w * b4.w;
        }
        __syncthreads();
    }

#pragma unroll
    for (int i = 0; i < 4; i++) {
        int m = m0 + ty * 4 + i;
        int n = n0 + tx * 4;
        size_t off = (size_t)m * N + n;
        float4 r;
        r.x = apply_epi<EPI>(acc[i][0], bias, res, off + 0, n + 0);
        r.y = apply_epi<EPI>(acc[i][1], bias, res, off + 1, n + 1);
        r.z = apply_epi<EPI>(acc[i][2], bias, res, off + 2, n + 2);
        r.w = apply_epi<EPI>(acc[i][3], bias, res, off + 3, n + 3);
        *(float4*)(C + off) = r;
    }
}

// ---------------------------------------------------------------------------
// Causal depthwise conv (width 4) + bias + SiLU.
// xin lives in xz[:, 0:1024] (row stride 2048). One thread per (b,t,d).
// ---------------------------------------------------------------------------
__global__ __launch_bounds__(256) void conv_silu_kernel(
    const float* __restrict__ xz, const float* __restrict__ cw,
    const float* __restrict__ cb, float* __restrict__ xc) {
    int idx = blockIdx.x * 256 + threadIdx.x;  // 0 .. 4M-1
    int d = idx & (D_INNER - 1);
    int t = (idx >> 10) & (L_SEQ - 1);
    int b = idx >> 20;
    float acc = cb[d];
    const float* base = xz + (size_t)(b * L_SEQ) * (2 * D_INNER) + d;
#pragma unroll
    for (int j = 0; j < 4; j++) {
        int tt = t - 3 + j;
        if (tt >= 0) acc += cw[d * 4 + j] * base[(size_t)tt * (2 * D_INNER)];
    }
    xc[idx] = acc / (1.f + expf(-acc));
}

// ---------------------------------------------------------------------------
// Selective scan, fused with D-skip + z-gate epilogue.
// Thread layout: tid = dl*16 + s (16 d-channels x 16 states per block).
// Grid: 256 blocks = 4 b x 64 d-chunks. Recurrence per (b,d,s):
//   h = exp(dt*A)*h + dt*B*xc ; y = sum_s h*C ; out=(y+D*xc)*silu(z)
// ---------------------------------------------------------------------------
__global__ __launch_bounds__(256) void scan_kernel(
    const float* __restrict__ dt, const float* __restrict__ xc,
    const float* __restrict__ dbl, const float* __restrict__ xz,
    const float* __restrict__ A_log, const float* __restrict__ Dsk,
    float* __restrict__ y) {
    int tid = threadIdx.x;
    int s = tid & 15;
    int dl = tid >> 4;
    int blk = blockIdx.x;
    int b = blk >> 6;
    int dchunk = blk & 63;
    int d = dchunk * 16 + dl;
    float Aval = -expf(A_log[d * D_STATE + s]);
    float Dv = Dsk[d];
    float h = 0.f;
    size_t rbase = (size_t)b * L_SEQ;

    float dtv = dt[rbase * D_INNER + d];
    float xcv = xc[rbase * D_INNER + d];
    float Bv = dbl[rbase * 64 + DT_RANK + s];
    float Cv = dbl[rbase * 64 + DT_RANK + D_STATE + s];

    for (int t = 0; t < L_SEQ; t++) {
        float dt_n = 0.f, xc_n = 0.f, B_n = 0.f, C_n = 0.f;
        if (t < L_SEQ - 1) {
            size_t r = rbase + t + 1;
            dt_n = dt[r * D_INNER + d];
            xc_n = xc[r * D_INNER + d];
            B_n = dbl[r * 64 + DT_RANK + s];
            C_n = dbl[r * 64 + DT_RANK + D_STATE + s];
        }
        float dA = expf(dtv * Aval);
        h = dA * h + dtv * Bv * xcv;
        float p = h * Cv;
        p += __shfl_xor(p, 1);
        p += __shfl_xor(p, 2);
        p += __shfl_xor(p, 4);
        p += __shfl_xor(p, 8);
        if (s == 0) {
            size_t r = rbase + t;
            float zv = xz[r * (2 * D_INNER) + D_INNER + d];
            float yv = (p + Dv * xcv) * (zv / (1.f + expf(-zv)));
            y[r * D_INNER + d] = yv;
        }
        dtv = dt_n; xcv = xc_n; Bv = B_n; Cv = C_n;
    }
}

// ---------------------------------------------------------------------------
// Host launcher
// ---------------------------------------------------------------------------
extern "C" void kernel_launch(void* const* d_in, const int* in_sizes, int n_in,
                              void* d_out, int out_size, void* d_ws, size_t ws_size,
                              hipStream_t stream) {
    const float* x_in     = (const float*)d_in[0];
    const float* ln1_g    = (const float*)d_in[1];
    const float* ln1_b    = (const float*)d_in[2];
    const float* in_w     = (const float*)d_in[3];
    const float* conv_w   = (const float*)d_in[4];
    const float* conv_b   = (const float*)d_in[5];
    const float* xproj_w  = (const float*)d_in[6];
    const float* dtproj_w = (const float*)d_in[7];
    const float* dtproj_b = (const float*)d_in[8];
    const float* A_log    = (const float*)d_in[9];
    const float* D_skip   = (const float*)d_in[10];
    const float* out_w    = (const float*)d_in[11];
    const float* ln2_g    = (const float*)d_in[12];
    const float* ln2_b    = (const float*)d_in[13];
    const float* mlp_w1   = (const float*)d_in[14];
    const float* mlp_b1   = (const float*)d_in[15];
    const float* mlp_w2   = (const float*)d_in[16];
    const float* mlp_b2   = (const float*)d_in[17];

    float* ws = (float*)d_ws;
    float* x_buf = ws;                        // 4096*512   = 2,097,152
    float* xn    = x_buf + 2097152;           // 4096*512
    float* xz    = xn + 2097152;              // 4096*2048  = 8,388,608
    float* xc    = xz + 8388608;              // 4096*1024  = 4,194,304
    float* dbl   = xc + 4194304;              // 4096*64    = 262,144
    float* dt    = dbl + 262144;              // 4096*1024
    float* yc    = dt + 4194304;              // 4096*1024

    for (int d = 0; d < 5; d++) {
        const float* xsrc = (d == 0) ? x_in : x_buf;

        // LN1
        ln_kernel<<<NROWS, 64, 0, stream>>>(xsrc, ln1_g + d * 512, ln1_b + d * 512, xn);
        // in_proj: xn @ in_w^T -> xz  (4096 x 2048, K=512)
        gemm_kernel<0><<<dim3(2048 / BN, NROWS / BM), 256, 0, stream>>>(
            xn, in_w + (size_t)d * 2048 * 512, nullptr, nullptr, xz, NROWS, 2048, 512, 512);
        // conv + silu -> xc
        conv_silu_kernel<<<(NROWS * D_INNER) / 256, 256, 0, stream>>>(
            xz, conv_w + d * 4096, conv_b + d * 1024, xc);
        // xproj: xc @ xproj_w^T -> dbl  (4096 x 64, K=1024)
        gemm_kernel<0><<<dim3(64 / BN, NROWS / BM), 256, 0, stream>>>(
            xc, xproj_w + (size_t)d * 64 * 1024, nullptr, nullptr, dbl, NROWS, 64, 1024, 1024);
        // dtproj + softplus: dbl[:, :32] @ dtproj_w^T + b -> dt (4096 x 1024, K=32, lda=64)
        gemm_kernel<1><<<dim3(1024 / BN, NROWS / BM), 256, 0, stream>>>(
            dbl, dtproj_w + (size_t)d * 1024 * 32, dtproj_b + d * 1024, nullptr, dt,
            NROWS, 1024, 32, 64);
        // selective scan fused with D-skip + z-gate -> yc
        scan_kernel<<<256, 256, 0, stream>>>(dt, xc, dbl, xz, A_log + d * 16384,
                                             D_skip + d * 1024, yc);
        // out_proj + residual: yc @ out_w^T + xsrc -> x_buf (4096 x 512, K=1024)
        gemm_kernel<2><<<dim3(512 / BN, NROWS / BM), 256, 0, stream>>>(
            yc, out_w + (size_t)d * 512 * 1024, nullptr, xsrc, x_buf, NROWS, 512, 1024, 1024);
        // LN2
        ln_kernel<<<NROWS, 64, 0, stream>>>(x_buf, ln2_g + d * 512, ln2_b + d * 512, xn);
        // mlp1 + bias + gelu: xn @ mlp_w1^T -> xz (reused as h1, 4096 x 1024, K=512)
        gemm_kernel<3><<<dim3(1024 / BN, NROWS / BM), 256, 0, stream>>>(
            xn, mlp_w1 + (size_t)d * 1024 * 512, mlp_b1 + d * 1024, nullptr, xz,
            NROWS, 1024, 512, 512);
        // mlp2 + bias + residual: h1 @ mlp_w2^T + b + x_buf -> x_buf (or d_out on last)
        float* dst = (d == 4) ? (float*)d_out : x_buf;
        gemm_kernel<4><<<dim3(512 / BN, NROWS / BM), 256, 0, stream>>>(
            xz, mlp_w2 + (size_t)d * 512 * 1024, mlp_b2 + d * 512, x_buf, dst,
            NROWS, 512, 1024, 1024);
    }
}

// Round 2
// 3209.929 us; speedup vs baseline: 1.7058x; 1.7058x over previous
//
#include <hip/hip_runtime.h>
#include <math.h>

#define D_MODEL 512
#define D_INNER 1024
#define L_SEQ 1024
#define BSZ 4
#define NROWS (BSZ * L_SEQ) /* 4096 */
#define DT_RANK 32
#define D_STATE 16
#define CHUNK 128
#define NCHUNK (L_SEQ / CHUNK) /* 8 */

// ---------------------------------------------------------------------------
// LayerNorm: one wave (64 lanes) per row of 512
// ---------------------------------------------------------------------------
__global__ __launch_bounds__(64) void ln_kernel(const float* __restrict__ x,
                                                const float* __restrict__ g,
                                                const float* __restrict__ b,
                                                float* __restrict__ out) {
    int row = blockIdx.x;
    int lane = threadIdx.x;
    const float* xr = x + (size_t)row * D_MODEL;
    float4 v0 = *(const float4*)(xr + lane * 8);
    float4 v1 = *(const float4*)(xr + lane * 8 + 4);
    float s = v0.x + v0.y + v0.z + v0.w + v1.x + v1.y + v1.z + v1.w;
    float ss = v0.x * v0.x + v0.y * v0.y + v0.z * v0.z + v0.w * v0.w +
               v1.x * v1.x + v1.y * v1.y + v1.z * v1.z + v1.w * v1.w;
#pragma unroll
    for (int o = 32; o >= 1; o >>= 1) {
        s += __shfl_xor(s, o);
        ss += __shfl_xor(ss, o);
    }
    float mean = s * (1.f / D_MODEL);
    float var = ss * (1.f / D_MODEL) - mean * mean;
    float rstd = rsqrtf(var + 1e-5f);
    float4 g0 = *(const float4*)(g + lane * 8);
    float4 g1 = *(const float4*)(g + lane * 8 + 4);
    float4 b0 = *(const float4*)(b + lane * 8);
    float4 b1 = *(const float4*)(b + lane * 8 + 4);
    float4 o0, o1;
    o0.x = (v0.x - mean) * rstd * g0.x + b0.x;
    o0.y = (v0.y - mean) * rstd * g0.y + b0.y;
    o0.z = (v0.z - mean) * rstd * g0.z + b0.z;
    o0.w = (v0.w - mean) * rstd * g0.w + b0.w;
    o1.x = (v1.x - mean) * rstd * g1.x + b1.x;
    o1.y = (v1.y - mean) * rstd * g1.y + b1.y;
    o1.z = (v1.z - mean) * rstd * g1.z + b1.z;
    o1.w = (v1.w - mean) * rstd * g1.w + b1.w;
    float* orow = out + (size_t)row * D_MODEL;
    *(float4*)(orow + lane * 8) = o0;
    *(float4*)(orow + lane * 8 + 4) = o1;
}

// ---------------------------------------------------------------------------
// Generic tiled fp32 GEMM: C[m,n] = epi( sum_k A[m,k]*W[n,k] )
// EPI: 0 none, 1 bias+softplus, 2 +res, 3 bias+gelu, 4 bias+res
// Tile 64x64, BK=32, 256 threads, 4x4 per thread.
// ---------------------------------------------------------------------------
#define BM 64
#define BN 64
#define BKK 32

template <int EPI>
__device__ inline float apply_epi(float v, const float* __restrict__ bias,
                                  const float* __restrict__ res, size_t off, int n) {
    if (EPI == 1) {
        float t = v + bias[n];
        return (t > 20.f) ? t : log1pf(expf(t));
    } else if (EPI == 2) {
        return v + res[off];
    } else if (EPI == 3) {
        float t = v + bias[n];
        return 0.5f * t * (1.f + erff(t * 0.70710678118654752f));
    } else if (EPI == 4) {
        return v + bias[n] + res[off];
    }
    return v;
}

template <int EPI>
__global__ __launch_bounds__(256) void gemm_kernel(
    const float* __restrict__ A, const float* __restrict__ W,
    const float* __restrict__ bias, const float* __restrict__ res,
    float* __restrict__ C, int M, int N, int K, int lda) {
    __shared__ __align__(16) float As[BKK][BM + 4];
    __shared__ __align__(16) float Ws[BKK][BN + 4];
    int tid = threadIdx.x;
    int m0 = blockIdx.y * BM;
    int n0 = blockIdx.x * BN;
    int ty = tid >> 4;   // 0..15
    int tx = tid & 15;   // 0..15
    float acc[4][4] = {};

    for (int k0 = 0; k0 < K; k0 += BKK) {
#pragma unroll
        for (int i = 0; i < 2; i++) {
            int e = tid + i * 256;       // 0..511 over 64x8 float4 grid
            int row = e >> 3;            // 0..63
            int c4 = (e & 7) * 4;        // 0,4,..,28
            float4 av = *(const float4*)(A + (size_t)(m0 + row) * lda + k0 + c4);
            As[c4 + 0][row] = av.x;
            As[c4 + 1][row] = av.y;
            As[c4 + 2][row] = av.z;
            As[c4 + 3][row] = av.w;
            float4 wv = *(const float4*)(W + (size_t)(n0 + row) * K + k0 + c4);
            Ws[c4 + 0][row] = wv.x;
            Ws[c4 + 1][row] = wv.y;
            Ws[c4 + 2][row] = wv.z;
            Ws[c4 + 3][row] = wv.w;
        }
        __syncthreads();
#pragma unroll
        for (int kk = 0; kk < BKK; kk++) {
            float4 a4 = *(const float4*)&As[kk][ty * 4];
            float4 b4 = *(const float4*)&Ws[kk][tx * 4];
            acc[0][0] += a4.x * b4.x; acc[0][1] += a4.x * b4.y;
            acc[0][2] += a4.x * b4.z; acc[0][3] += a4.x * b4.w;
            acc[1][0] += a4.y * b4.x; acc[1][1] += a4.y * b4.y;
            acc[1][2] += a4.y * b4.z; acc[1][3] += a4.y * b4.w;
            acc[2][0] += a4.z * b4.x; acc[2][1] += a4.z * b4.y;
            acc[2][2] += a4.z * b4.z; acc[2][3] += a4.z * b4.w;
            acc[3][0] += a4.w * b4.x; acc[3][1] += a4.w * b4.y;
            acc[3][2] += a4.w * b4.z; acc[3][3] += a4.w * b4.w;
        }
        __syncthreads();
    }

#pragma unroll
    for (int i = 0; i < 4; i++) {
        int m = m0 + ty * 4 + i;
        int n = n0 + tx * 4;
        size_t off = (size_t)m * N + n;
        float4 r;
        r.x = apply_epi<EPI>(acc[i][0], bias, res, off + 0, n + 0);
        r.y = apply_epi<EPI>(acc[i][1], bias, res, off + 1, n + 1);
        r.z = apply_epi<EPI>(acc[i][2], bias, res, off + 2, n + 2);
        r.w = apply_epi<EPI>(acc[i][3], bias, res, off + 3, n + 3);
        *(float4*)(C + off) = r;
    }
}

// ---------------------------------------------------------------------------
// Causal depthwise conv (width 4) + bias + SiLU.
// ---------------------------------------------------------------------------
__global__ __launch_bounds__(256) void conv_silu_kernel(
    const float* __restrict__ xz, const float* __restrict__ cw,
    const float* __restrict__ cb, float* __restrict__ xc) {
    int idx = blockIdx.x * 256 + threadIdx.x;  // 0 .. 4M-1
    int d = idx & (D_INNER - 1);
    int t = (idx >> 10) & (L_SEQ - 1);
    int b = idx >> 20;
    float acc = cb[d];
    const float* base = xz + (size_t)(b * L_SEQ) * (2 * D_INNER) + d;
#pragma unroll
    for (int j = 0; j < 4; j++) {
        int tt = t - 3 + j;
        if (tt >= 0) acc += cw[d * 4 + j] * base[(size_t)tt * (2 * D_INNER)];
    }
    xc[idx] = acc / (1.f + expf(-acc));
}

// ---------------------------------------------------------------------------
// Chunked selective scan. Recurrence h_t = a_t h_{t-1} + b_t is linear,
// so: pass1 computes per-chunk (P=prod a, S=h from 0); pass2 serially
// composes chunks (8 steps) to get each chunk's incoming state; pass3
// replays chunks from the true incoming state and emits gated output.
// Thread layout in pass1/3: tid = dl*16 + s. Block = 16 d x 16 s.
// ---------------------------------------------------------------------------
__global__ __launch_bounds__(256) void scan_pass1(
    const float* __restrict__ dt, const float* __restrict__ xc,
    const float* __restrict__ dbl, const float* __restrict__ A_log,
    float* __restrict__ Pbuf, float* __restrict__ Sbuf) {
    int tid = threadIdx.x;
    int s = tid & 15;
    int dl = tid >> 4;
    int blk = blockIdx.x;            // b*(NCHUNK*64) + c*64 + dchunk
    int dchunk = blk & 63;
    int c = (blk >> 6) & (NCHUNK - 1);
    int b = blk >> 9;
    int d = dchunk * 16 + dl;
    float Aval = -expf(A_log[d * D_STATE + s]);
    float h = 0.f, P = 1.f;
    size_t rbase = (size_t)b * L_SEQ + (size_t)c * CHUNK;

    float dtv = dt[rbase * D_INNER + d];
    float xcv = xc[rbase * D_INNER + d];
    float Bv = dbl[rbase * 64 + DT_RANK + s];

    for (int t = 0; t < CHUNK; t++) {
        float dt_n = 0.f, xc_n = 0.f, B_n = 0.f;
        if (t < CHUNK - 1) {
            size_t r = rbase + t + 1;
            dt_n = dt[r * D_INNER + d];
            xc_n = xc[r * D_INNER + d];
            B_n = dbl[r * 64 + DT_RANK + s];
        }
        float a = expf(dtv * Aval);
        h = a * h + dtv * Bv * xcv;
        P *= a;
        dtv = dt_n; xcv = xc_n; Bv = B_n;
    }
    size_t o = (((size_t)b * NCHUNK + c) * D_INNER + d) * D_STATE + s;
    Pbuf[o] = P;
    Sbuf[o] = h;
}

__global__ __launch_bounds__(256) void scan_pass2(
    const float* __restrict__ Pbuf, const float* __restrict__ Sbuf,
    float* __restrict__ Hin) {
    int idx = blockIdx.x * 256 + threadIdx.x;  // over B*D_INNER*D_STATE
    int sd = idx & 16383;                      // d*16+s within batch
    int b = idx >> 14;
    float H = 0.f;
#pragma unroll
    for (int c = 0; c < NCHUNK; c++) {
        size_t o = ((size_t)(b * NCHUNK + c) << 14) + sd;
        Hin[o] = H;
        H = Pbuf[o] * H + Sbuf[o];
    }
}

__global__ __launch_bounds__(256) void scan_pass3(
    const float* __restrict__ dt, const float* __restrict__ xc,
    const float* __restrict__ dbl, const float* __restrict__ xz,
    const float* __restrict__ A_log, const float* __restrict__ Dsk,
    const float* __restrict__ Hin, float* __restrict__ y) {
    int tid = threadIdx.x;
    int s = tid & 15;
    int dl = tid >> 4;
    int blk = blockIdx.x;
    int dchunk = blk & 63;
    int c = (blk >> 6) & (NCHUNK - 1);
    int b = blk >> 9;
    int d = dchunk * 16 + dl;
    float Aval = -expf(A_log[d * D_STATE + s]);
    float Dv = Dsk[d];
    float h = Hin[(((size_t)b * NCHUNK + c) * D_INNER + d) * D_STATE + s];
    size_t rbase = (size_t)b * L_SEQ + (size_t)c * CHUNK;

    float dtv = dt[rbase * D_INNER + d];
    float xcv = xc[rbase * D_INNER + d];
    float Bv = dbl[rbase * 64 + DT_RANK + s];
    float Cv = dbl[rbase * 64 + DT_RANK + D_STATE + s];

    for (int t = 0; t < CHUNK; t++) {
        float dt_n = 0.f, xc_n = 0.f, B_n = 0.f, C_n = 0.f;
        if (t < CHUNK - 1) {
            size_t r = rbase + t + 1;
            dt_n = dt[r * D_INNER + d];
            xc_n = xc[r * D_INNER + d];
            B_n = dbl[r * 64 + DT_RANK + s];
            C_n = dbl[r * 64 + DT_RANK + D_STATE + s];
        }
        float a = expf(dtv * Aval);
        h = a * h + dtv * Bv * xcv;
        float p = h * Cv;
        p += __shfl_xor(p, 1);
        p += __shfl_xor(p, 2);
        p += __shfl_xor(p, 4);
        p += __shfl_xor(p, 8);
        if (s == 0) {
            size_t r = rbase + t;
            float zv = xz[r * (2 * D_INNER) + D_INNER + d];
            float yv = (p + Dv * xcv) * (zv / (1.f + expf(-zv)));
            y[r * D_INNER + d] = yv;
        }
        dtv = dt_n; xcv = xc_n; Bv = B_n; Cv = C_n;
    }
}

// ---------------------------------------------------------------------------
// Host launcher
// ---------------------------------------------------------------------------
extern "C" void kernel_launch(void* const* d_in, const int* in_sizes, int n_in,
                              void* d_out, int out_size, void* d_ws, size_t ws_size,
                              hipStream_t stream) {
    const float* x_in     = (const float*)d_in[0];
    const float* ln1_g    = (const float*)d_in[1];
    const float* ln1_b    = (const float*)d_in[2];
    const float* in_w     = (const float*)d_in[3];
    const float* conv_w   = (const float*)d_in[4];
    const float* conv_b   = (const float*)d_in[5];
    const float* xproj_w  = (const float*)d_in[6];
    const float* dtproj_w = (const float*)d_in[7];
    const float* dtproj_b = (const float*)d_in[8];
    const float* A_log    = (const float*)d_in[9];
    const float* D_skip   = (const float*)d_in[10];
    const float* out_w    = (const float*)d_in[11];
    const float* ln2_g    = (const float*)d_in[12];
    const float* ln2_b    = (const float*)d_in[13];
    const float* mlp_w1   = (const float*)d_in[14];
    const float* mlp_b1   = (const float*)d_in[15];
    const float* mlp_w2   = (const float*)d_in[16];
    const float* mlp_b2   = (const float*)d_in[17];

    float* ws = (float*)d_ws;
    float* x_buf = ws;                        // 4096*512
    float* xn    = x_buf + 2097152;           // 4096*512
    float* xz    = xn + 2097152;              // 4096*2048
    float* xc    = xz + 8388608;              // 4096*1024
    float* dbl   = xc + 4194304;              // 4096*64
    float* dt    = dbl + 262144;              // 4096*1024
    float* yc    = dt + 4194304;              // 4096*1024
    float* Pbuf  = yc + 4194304;              // 4*8*1024*16 = 524288
    float* Sbuf  = Pbuf + 524288;             // 524288
    float* Hin   = Sbuf + 524288;             // 524288

    for (int d = 0; d < 5; d++) {
        const float* xsrc = (d == 0) ? x_in : x_buf;

        // LN1
        ln_kernel<<<NROWS, 64, 0, stream>>>(xsrc, ln1_g + d * 512, ln1_b + d * 512, xn);
        // in_proj: xn @ in_w^T -> xz  (4096 x 2048, K=512)
        gemm_kernel<0><<<dim3(2048 / BN, NROWS / BM), 256, 0, stream>>>(
            xn, in_w + (size_t)d * 2048 * 512, nullptr, nullptr, xz, NROWS, 2048, 512, 512);
        // conv + silu -> xc
        conv_silu_kernel<<<(NROWS * D_INNER) / 256, 256, 0, stream>>>(
            xz, conv_w + d * 4096, conv_b + d * 1024, xc);
        // xproj: xc @ xproj_w^T -> dbl  (4096 x 64, K=1024)
        gemm_kernel<0><<<dim3(64 / BN, NROWS / BM), 256, 0, stream>>>(
            xc, xproj_w + (size_t)d * 64 * 1024, nullptr, nullptr, dbl, NROWS, 64, 1024, 1024);
        // dtproj + softplus: dbl[:, :32] @ dtproj_w^T + b -> dt (4096 x 1024, K=32, lda=64)
        gemm_kernel<1><<<dim3(1024 / BN, NROWS / BM), 256, 0, stream>>>(
            dbl, dtproj_w + (size_t)d * 1024 * 32, dtproj_b + d * 1024, nullptr, dt,
            NROWS, 1024, 32, 64);
        // chunked selective scan (3 passes), fused D-skip + z-gate -> yc
        scan_pass1<<<BSZ * NCHUNK * 64, 256, 0, stream>>>(
            dt, xc, dbl, A_log + d * 16384, Pbuf, Sbuf);
        scan_pass2<<<(BSZ * D_INNER * D_STATE) / 256, 256, 0, stream>>>(Pbuf, Sbuf, Hin);
        scan_pass3<<<BSZ * NCHUNK * 64, 256, 0, stream>>>(
            dt, xc, dbl, xz, A_log + d * 16384, D_skip + d * 1024, Hin, yc);
        // out_proj + residual: yc @ out_w^T + xsrc -> x_buf (4096 x 512, K=1024)
        gemm_kernel<2><<<dim3(512 / BN, NROWS / BM), 256, 0, stream>>>(
            yc, out_w + (size_t)d * 512 * 1024, nullptr, xsrc, x_buf, NROWS, 512, 1024, 1024);
        // LN2
        ln_kernel<<<NROWS, 64, 0, stream>>>(x_buf, ln2_g + d * 512, ln2_b + d * 512, xn);
        // mlp1 + bias + gelu: xn @ mlp_w1^T -> xz (reused as h1, 4096 x 1024, K=512)
        gemm_kernel<3><<<dim3(1024 / BN, NROWS / BM), 256, 0, stream>>>(
            xn, mlp_w1 + (size_t)d * 1024 * 512, mlp_b1 + d * 1024, nullptr, xz,
            NROWS, 1024, 512, 512);
        // mlp2 + bias + residual: h1 @ mlp_w2^T + b + x_buf -> x_buf (or d_out on last)
        float* dst = (d == 4) ? (float*)d_out : x_buf;
        gemm_kernel<4><<<dim3(512 / BN, NROWS / BM), 256, 0, stream>>>(
            xz, mlp_w2 + (size_t)d * 512 * 1024, mlp_b2 + d * 512, x_buf, dst,
            NROWS, 512, 1024, 1024);
    }
}

// Round 3
// 1731.995 us; speedup vs baseline: 3.1614x; 1.8533x over previous
//
#include <hip/hip_runtime.h>
#include <math.h>

#define D_MODEL 512
#define D_INNER 1024
#define L_SEQ 1024
#define BSZ 4
#define NROWS (BSZ * L_SEQ) /* 4096 */
#define DT_RANK 32
#define D_STATE 16
#define CHUNK 128
#define NCHUNK (L_SEQ / CHUNK) /* 8 */

typedef unsigned short ushort_t;
typedef __attribute__((ext_vector_type(8))) short short8;
typedef __attribute__((ext_vector_type(4))) float f32x4;

__device__ inline ushort_t bf16_rn(float f) {
    union { float f; unsigned u; } v; v.f = f;
    unsigned r = v.u + 0x7fffu + ((v.u >> 16) & 1u);
    return (ushort_t)(r >> 16);
}

// ---------------------------------------------------------------------------
// fp32 -> bf16 tensor conversion (weights, once per launch)
// ---------------------------------------------------------------------------
__global__ __launch_bounds__(256) void f2b_kernel(const float* __restrict__ src,
                                                  ushort_t* __restrict__ dst, int n4) {
    int i = blockIdx.x * 256 + threadIdx.x;
    if (i < n4) {
        float4 v = ((const float4*)src)[i];
        uint2 pk;
        pk.x = (unsigned)bf16_rn(v.x) | ((unsigned)bf16_rn(v.y) << 16);
        pk.y = (unsigned)bf16_rn(v.z) | ((unsigned)bf16_rn(v.w) << 16);
        ((uint2*)dst)[i] = pk;
    }
}

// ---------------------------------------------------------------------------
// LayerNorm: one wave per row of 512, bf16 output (feeds a GEMM)
// ---------------------------------------------------------------------------
__global__ __launch_bounds__(64) void ln_kernel(const float* __restrict__ x,
                                                const float* __restrict__ g,
                                                const float* __restrict__ b,
                                                ushort_t* __restrict__ out) {
    int row = blockIdx.x;
    int lane = threadIdx.x;
    const float* xr = x + (size_t)row * D_MODEL;
    float4 v0 = *(const float4*)(xr + lane * 8);
    float4 v1 = *(const float4*)(xr + lane * 8 + 4);
    float s = v0.x + v0.y + v0.z + v0.w + v1.x + v1.y + v1.z + v1.w;
    float ss = v0.x * v0.x + v0.y * v0.y + v0.z * v0.z + v0.w * v0.w +
               v1.x * v1.x + v1.y * v1.y + v1.z * v1.z + v1.w * v1.w;
#pragma unroll
    for (int o = 32; o >= 1; o >>= 1) {
        s += __shfl_xor(s, o);
        ss += __shfl_xor(ss, o);
    }
    float mean = s * (1.f / D_MODEL);
    float var = ss * (1.f / D_MODEL) - mean * mean;
    float rstd = rsqrtf(var + 1e-5f);
    float4 g0 = *(const float4*)(g + lane * 8);
    float4 g1 = *(const float4*)(g + lane * 8 + 4);
    float4 b0 = *(const float4*)(b + lane * 8);
    float4 b1 = *(const float4*)(b + lane * 8 + 4);
    float o0 = (v0.x - mean) * rstd * g0.x + b0.x;
    float o1 = (v0.y - mean) * rstd * g0.y + b0.y;
    float o2 = (v0.z - mean) * rstd * g0.z + b0.z;
    float o3 = (v0.w - mean) * rstd * g0.w + b0.w;
    float o4 = (v1.x - mean) * rstd * g1.x + b1.x;
    float o5 = (v1.y - mean) * rstd * g1.y + b1.y;
    float o6 = (v1.z - mean) * rstd * g1.z + b1.z;
    float o7 = (v1.w - mean) * rstd * g1.w + b1.w;
    uint4 pk;
    pk.x = (unsigned)bf16_rn(o0) | ((unsigned)bf16_rn(o1) << 16);
    pk.y = (unsigned)bf16_rn(o2) | ((unsigned)bf16_rn(o3) << 16);
    pk.z = (unsigned)bf16_rn(o4) | ((unsigned)bf16_rn(o5) << 16);
    pk.w = (unsigned)bf16_rn(o6) | ((unsigned)bf16_rn(o7) << 16);
    *(uint4*)(out + (size_t)row * D_MODEL + lane * 8) = pk;
}

// ---------------------------------------------------------------------------
// bf16 MFMA GEMM: C[m,n] = epi( sum_k A[m,k]*W[n,k] ), fp32 accumulate.
// A [M,K] bf16 row-major, W [N,K] bf16 row-major. 256 threads = 2x2 waves.
// Tiles: BMt x BNt block, (BMt/2)x(BNt/2) per wave, 16x16x32 MFMA.
// Staging: global_load_lds 16B, LDS row-major [rows][32] bf16 (64 B/row).
// EPI: 0 fp32  1 bias+softplus fp32  2 +res fp32  3 bias+gelu -> bf16
//      4 bias+res fp32  5 fp32 + bf16 compact copy of cols<32 (dtr)
// ---------------------------------------------------------------------------
template <int BMt, int BNt, int EPI>
__global__ __launch_bounds__(256) void bgemm_kernel(
    const ushort_t* __restrict__ A, const ushort_t* __restrict__ W,
    const float* __restrict__ bias, const float* __restrict__ res,
    float* __restrict__ C, ushort_t* __restrict__ Cb,
    int M, int N, int K) {
    constexpr int WM = BMt / 2, WN = BNt / 2;
    constexpr int MT = WM / 16, NT = WN / 16;
    constexpr int ACH = BMt * 4;            // 16B chunks in A tile
    constexpr int TOT = ACH + BNt * 4;
    constexpr int NIT = TOT / 256;
    __shared__ ushort_t As[BMt * 32];
    __shared__ ushort_t Ws[BNt * 32];

    int tid = threadIdx.x;
    int lane = tid & 63;
    int wv = tid >> 6;
    int wrow = wv >> 1, wcol = wv & 1;
    int m0 = blockIdx.y * BMt, n0 = blockIdx.x * BNt;
    int lrow = lane & 15;
    int ko = lane >> 4;

    f32x4 acc[MT][NT] = {};

    for (int k0 = 0; k0 < K; k0 += 32) {
#pragma unroll
        for (int i = 0; i < NIT; i++) {
            int e = tid + i * 256;
            const ushort_t* gp;
            ushort_t* lp;
            if (e < ACH) {
                int row = e >> 2, ch = e & 3;
                gp = A + (size_t)(m0 + row) * K + k0 + ch * 8;
                lp = As + e * 8;
            } else {
                int e2 = e - ACH;
                int row = e2 >> 2, ch = e2 & 3;
                gp = W + (size_t)(n0 + row) * K + k0 + ch * 8;
                lp = Ws + e2 * 8;
            }
            __builtin_amdgcn_global_load_lds(
                (const __attribute__((address_space(1))) void*)gp,
                (__attribute__((address_space(3))) void*)lp, 16, 0, 0);
        }
        __syncthreads();
        short8 a[MT], b[NT];
#pragma unroll
        for (int mt = 0; mt < MT; mt++) {
            int ml = wrow * WM + mt * 16 + lrow;
            a[mt] = *(const short8*)(As + ml * 32 + ko * 8);
        }
#pragma unroll
        for (int nt = 0; nt < NT; nt++) {
            int nl = wcol * WN + nt * 16 + lrow;
            b[nt] = *(const short8*)(Ws + nl * 32 + ko * 8);
        }
#pragma unroll
        for (int mt = 0; mt < MT; mt++)
#pragma unroll
            for (int nt = 0; nt < NT; nt++)
                acc[mt][nt] = __builtin_amdgcn_mfma_f32_16x16x32_bf16(
                    a[mt], b[nt], acc[mt][nt], 0, 0, 0);
        __syncthreads();
    }

    int r4 = lane >> 4;
#pragma unroll
    for (int mt = 0; mt < MT; mt++) {
#pragma unroll
        for (int nt = 0; nt < NT; nt++) {
            int n = n0 + wcol * WN + nt * 16 + lrow;
#pragma unroll
            for (int i = 0; i < 4; i++) {
                int m = m0 + wrow * WM + mt * 16 + r4 * 4 + i;
                float v = acc[mt][nt][i];
                size_t off = (size_t)m * N + n;
                if (EPI == 0) {
                    C[off] = v;
                } else if (EPI == 1) {
                    float t = v + bias[n];
                    C[off] = (t > 20.f) ? t : log1pf(expf(t));
                } else if (EPI == 2) {
                    C[off] = v + res[off];
                } else if (EPI == 3) {
                    float t = v + bias[n];
                    Cb[off] = bf16_rn(0.5f * t * (1.f + erff(t * 0.70710678118654752f)));
                } else if (EPI == 4) {
                    C[off] = v + bias[n] + res[off];
                } else if (EPI == 5) {
                    C[off] = v;
                    if (n < DT_RANK) Cb[(size_t)m * DT_RANK + n] = bf16_rn(v);
                }
            }
        }
    }
}

// ---------------------------------------------------------------------------
// Causal depthwise conv (width 4) + bias + SiLU; dual fp32/bf16 output.
// ---------------------------------------------------------------------------
__global__ __launch_bounds__(256) void conv_silu_kernel(
    const float* __restrict__ xz, const float* __restrict__ cw,
    const float* __restrict__ cb, float* __restrict__ xc_f,
    ushort_t* __restrict__ xc_b) {
    int idx = blockIdx.x * 256 + threadIdx.x;  // 0 .. 4M-1
    int d = idx & (D_INNER - 1);
    int t = (idx >> 10) & (L_SEQ - 1);
    int b = idx >> 20;
    float acc = cb[d];
    const float* base = xz + (size_t)(b * L_SEQ) * (2 * D_INNER) + d;
#pragma unroll
    for (int j = 0; j < 4; j++) {
        int tt = t - 3 + j;
        if (tt >= 0) acc += cw[d * 4 + j] * base[(size_t)tt * (2 * D_INNER)];
    }
    float s = acc / (1.f + expf(-acc));
    xc_f[idx] = s;
    xc_b[idx] = bf16_rn(s);
}

// ---------------------------------------------------------------------------
// Chunked selective scan (3 passes). pass3 writes bf16 yc (feeds out_proj).
// ---------------------------------------------------------------------------
__global__ __launch_bounds__(256) void scan_pass1(
    const float* __restrict__ dt, const float* __restrict__ xc,
    const float* __restrict__ dbl, const float* __restrict__ A_log,
    float* __restrict__ Pbuf, float* __restrict__ Sbuf) {
    int tid = threadIdx.x;
    int s = tid & 15;
    int dl = tid >> 4;
    int blk = blockIdx.x;
    int dchunk = blk & 63;
    int c = (blk >> 6) & (NCHUNK - 1);
    int b = blk >> 9;
    int d = dchunk * 16 + dl;
    float Aval = -expf(A_log[d * D_STATE + s]);
    float h = 0.f, P = 1.f;
    size_t rbase = (size_t)b * L_SEQ + (size_t)c * CHUNK;

    float dtv = dt[rbase * D_INNER + d];
    float xcv = xc[rbase * D_INNER + d];
    float Bv = dbl[rbase * 64 + DT_RANK + s];

    for (int t = 0; t < CHUNK; t++) {
        float dt_n = 0.f, xc_n = 0.f, B_n = 0.f;
        if (t < CHUNK - 1) {
            size_t r = rbase + t + 1;
            dt_n = dt[r * D_INNER + d];
            xc_n = xc[r * D_INNER + d];
            B_n = dbl[r * 64 + DT_RANK + s];
        }
        float a = expf(dtv * Aval);
        h = a * h + dtv * Bv * xcv;
        P *= a;
        dtv = dt_n; xcv = xc_n; Bv = B_n;
    }
    size_t o = (((size_t)b * NCHUNK + c) * D_INNER + d) * D_STATE + s;
    Pbuf[o] = P;
    Sbuf[o] = h;
}

__global__ __launch_bounds__(256) void scan_pass2(
    const float* __restrict__ Pbuf, const float* __restrict__ Sbuf,
    float* __restrict__ Hin) {
    int idx = blockIdx.x * 256 + threadIdx.x;
    int sd = idx & 16383;
    int b = idx >> 14;
    float H = 0.f;
#pragma unroll
    for (int c = 0; c < NCHUNK; c++) {
        size_t o = ((size_t)(b * NCHUNK + c) << 14) + sd;
        Hin[o] = H;
        H = Pbuf[o] * H + Sbuf[o];
    }
}

__global__ __launch_bounds__(256) void scan_pass3(
    const float* __restrict__ dt, const float* __restrict__ xc,
    const float* __restrict__ dbl, const float* __restrict__ xz,
    const float* __restrict__ A_log, const float* __restrict__ Dsk,
    const float* __restrict__ Hin, ushort_t* __restrict__ y) {
    int tid = threadIdx.x;
    int s = tid & 15;
    int dl = tid >> 4;
    int blk = blockIdx.x;
    int dchunk = blk & 63;
    int c = (blk >> 6) & (NCHUNK - 1);
    int b = blk >> 9;
    int d = dchunk * 16 + dl;
    float Aval = -expf(A_log[d * D_STATE + s]);
    float Dv = Dsk[d];
    float h = Hin[(((size_t)b * NCHUNK + c) * D_INNER + d) * D_STATE + s];
    size_t rbase = (size_t)b * L_SEQ + (size_t)c * CHUNK;

    float dtv = dt[rbase * D_INNER + d];
    float xcv = xc[rbase * D_INNER + d];
    float Bv = dbl[rbase * 64 + DT_RANK + s];
    float Cv = dbl[rbase * 64 + DT_RANK + D_STATE + s];

    for (int t = 0; t < CHUNK; t++) {
        float dt_n = 0.f, xc_n = 0.f, B_n = 0.f, C_n = 0.f;
        if (t < CHUNK - 1) {
            size_t r = rbase + t + 1;
            dt_n = dt[r * D_INNER + d];
            xc_n = xc[r * D_INNER + d];
            B_n = dbl[r * 64 + DT_RANK + s];
            C_n = dbl[r * 64 + DT_RANK + D_STATE + s];
        }
        float a = expf(dtv * Aval);
        h = a * h + dtv * Bv * xcv;
        float p = h * Cv;
        p += __shfl_xor(p, 1);
        p += __shfl_xor(p, 2);
        p += __shfl_xor(p, 4);
        p += __shfl_xor(p, 8);
        if (s == 0) {
            size_t r = rbase + t;
            float zv = xz[r * (2 * D_INNER) + D_INNER + d];
            float yv = (p + Dv * xcv) * (zv / (1.f + expf(-zv)));
            y[r * D_INNER + d] = bf16_rn(yv);
        }
        dtv = dt_n; xcv = xc_n; Bv = B_n; Cv = C_n;
    }
}

// ---------------------------------------------------------------------------
// Host launcher
// ---------------------------------------------------------------------------
extern "C" void kernel_launch(void* const* d_in, const int* in_sizes, int n_in,
                              void* d_out, int out_size, void* d_ws, size_t ws_size,
                              hipStream_t stream) {
    const float* x_in     = (const float*)d_in[0];
    const float* ln1_g    = (const float*)d_in[1];
    const float* ln1_b    = (const float*)d_in[2];
    const float* in_w     = (const float*)d_in[3];
    const float* conv_w   = (const float*)d_in[4];
    const float* conv_b   = (const float*)d_in[5];
    const float* xproj_w  = (const float*)d_in[6];
    const float* dtproj_w = (const float*)d_in[7];
    const float* dtproj_b = (const float*)d_in[8];
    const float* A_log    = (const float*)d_in[9];
    const float* D_skip   = (const float*)d_in[10];
    const float* out_w    = (const float*)d_in[11];
    const float* ln2_g    = (const float*)d_in[12];
    const float* ln2_b    = (const float*)d_in[13];
    const float* mlp_w1   = (const float*)d_in[14];
    const float* mlp_b1   = (const float*)d_in[15];
    const float* mlp_w2   = (const float*)d_in[16];
    const float* mlp_b2   = (const float*)d_in[17];

    char* p = (char*)d_ws;
    float* x_buf = (float*)p;        p += (size_t)NROWS * 512 * 4;        // 8 MB
    float* xz    = (float*)p;        p += (size_t)NROWS * 2048 * 4;       // 32 MB
    float* xc_f  = (float*)p;        p += (size_t)NROWS * 1024 * 4;       // 16 MB
    float* dbl   = (float*)p;        p += (size_t)NROWS * 64 * 4;         // 1 MB
    float* dt    = (float*)p;        p += (size_t)NROWS * 1024 * 4;       // 16 MB
    float* Pbuf  = (float*)p;        p += (size_t)BSZ * NCHUNK * 16384 * 4;
    float* Sbuf  = (float*)p;        p += (size_t)BSZ * NCHUNK * 16384 * 4;
    float* Hin   = (float*)p;        p += (size_t)BSZ * NCHUNK * 16384 * 4;
    ushort_t* xn_b  = (ushort_t*)p;  p += (size_t)NROWS * 512 * 2;        // 4 MB
    ushort_t* xc_b  = (ushort_t*)p;  p += (size_t)NROWS * 1024 * 2;       // 8 MB
    ushort_t* dtr_b = (ushort_t*)p;  p += (size_t)NROWS * 32 * 2;
    ushort_t* yc_b  = (ushort_t*)p;  p += (size_t)NROWS * 1024 * 2;       // 8 MB
    ushort_t* wi_b  = (ushort_t*)p;  p += (size_t)5 * 2048 * 512 * 2;
    ushort_t* wx_b  = (ushort_t*)p;  p += (size_t)5 * 64 * 1024 * 2;
    ushort_t* wd_b  = (ushort_t*)p;  p += (size_t)5 * 1024 * 32 * 2;
    ushort_t* wo_b  = (ushort_t*)p;  p += (size_t)5 * 512 * 1024 * 2;
    ushort_t* w1_b  = (ushort_t*)p;  p += (size_t)5 * 1024 * 512 * 2;
    ushort_t* w2_b  = (ushort_t*)p;  p += (size_t)5 * 512 * 1024 * 2;
    ushort_t* h1_b  = (ushort_t*)xz; // alias: xz is dead once mlp1 runs

    // weight conversion (every launch; inputs are re-restored by harness)
    f2b_kernel<<<(5 * 2048 * 512 / 4 + 255) / 256, 256, 0, stream>>>(in_w, wi_b, 5 * 2048 * 512 / 4);
    f2b_kernel<<<(5 * 64 * 1024 / 4 + 255) / 256, 256, 0, stream>>>(xproj_w, wx_b, 5 * 64 * 1024 / 4);
    f2b_kernel<<<(5 * 1024 * 32 / 4 + 255) / 256, 256, 0, stream>>>(dtproj_w, wd_b, 5 * 1024 * 32 / 4);
    f2b_kernel<<<(5 * 512 * 1024 / 4 + 255) / 256, 256, 0, stream>>>(out_w, wo_b, 5 * 512 * 1024 / 4);
    f2b_kernel<<<(5 * 1024 * 512 / 4 + 255) / 256, 256, 0, stream>>>(mlp_w1, w1_b, 5 * 1024 * 512 / 4);
    f2b_kernel<<<(5 * 512 * 1024 / 4 + 255) / 256, 256, 0, stream>>>(mlp_w2, w2_b, 5 * 512 * 1024 / 4);

    for (int d = 0; d < 5; d++) {
        const float* xsrc = (d == 0) ? x_in : x_buf;

        // LN1 -> bf16
        ln_kernel<<<NROWS, 64, 0, stream>>>(xsrc, ln1_g + d * 512, ln1_b + d * 512, xn_b);
        // in_proj: 4096x2048, K=512
        bgemm_kernel<128, 128, 0><<<dim3(16, 32), 256, 0, stream>>>(
            xn_b, wi_b + (size_t)d * 2048 * 512, nullptr, nullptr, xz, nullptr,
            NROWS, 2048, 512);
        // conv + silu
        conv_silu_kernel<<<(NROWS * D_INNER) / 256, 256, 0, stream>>>(
            xz, conv_w + d * 4096, conv_b + d * 1024, xc_f, xc_b);
        // xproj: 4096x64, K=1024 -> dbl fp32 + dtr bf16
        bgemm_kernel<64, 64, 5><<<dim3(1, 64), 256, 0, stream>>>(
            xc_b, wx_b + (size_t)d * 64 * 1024, nullptr, nullptr, dbl, dtr_b,
            NROWS, 64, 1024);
        // dtproj + softplus: 4096x1024, K=32
        bgemm_kernel<128, 128, 1><<<dim3(8, 32), 256, 0, stream>>>(
            dtr_b, wd_b + (size_t)d * 1024 * 32, dtproj_b + d * 1024, nullptr, dt, nullptr,
            NROWS, 1024, 32);
        // chunked scan
        scan_pass1<<<BSZ * NCHUNK * 64, 256, 0, stream>>>(
            dt, xc_f, dbl, A_log + d * 16384, Pbuf, Sbuf);
        scan_pass2<<<(BSZ * D_INNER * D_STATE) / 256, 256, 0, stream>>>(Pbuf, Sbuf, Hin);
        scan_pass3<<<BSZ * NCHUNK * 64, 256, 0, stream>>>(
            dt, xc_f, dbl, xz, A_log + d * 16384, D_skip + d * 1024, Hin, yc_b);
        // out_proj + residual: 4096x512, K=1024
        bgemm_kernel<128, 64, 2><<<dim3(8, 32), 256, 0, stream>>>(
            yc_b, wo_b + (size_t)d * 512 * 1024, nullptr, xsrc, x_buf, nullptr,
            NROWS, 512, 1024);
        // LN2 -> bf16
        ln_kernel<<<NROWS, 64, 0, stream>>>(x_buf, ln2_g + d * 512, ln2_b + d * 512, xn_b);
        // mlp1 + bias + gelu -> bf16 h1: 4096x1024, K=512
        bgemm_kernel<128, 128, 3><<<dim3(8, 32), 256, 0, stream>>>(
            xn_b, w1_b + (size_t)d * 1024 * 512, mlp_b1 + d * 1024, nullptr, nullptr, h1_b,
            NROWS, 1024, 512);
        // mlp2 + bias + residual: 4096x512, K=1024
        float* dst = (d == 4) ? (float*)d_out : x_buf;
        bgemm_kernel<128, 64, 4><<<dim3(8, 32), 256, 0, stream>>>(
            h1_b, w2_b + (size_t)d * 512 * 1024, mlp_b2 + d * 512, x_buf, dst, nullptr,
            NROWS, 512, 1024);
    }
}

// Round 4
// 1205.325 us; speedup vs baseline: 4.5427x; 1.4370x over previous
//
#include <hip/hip_runtime.h>
#include <math.h>

#define D_MODEL 512
#define D_INNER 1024
#define L_SEQ 1024
#define BSZ 4
#define NROWS (BSZ * L_SEQ) /* 4096 */
#define DT_RANK 32
#define D_STATE 16
#define CHUNK 32
#define NCHUNK (L_SEQ / CHUNK) /* 32 */

typedef unsigned short ushort_t;
typedef __attribute__((ext_vector_type(8))) short short8;
typedef __attribute__((ext_vector_type(4))) float f32x4;

__device__ inline ushort_t bf16_rn(float f) {
    union { float f; unsigned u; } v; v.f = f;
    unsigned r = v.u + 0x7fffu + ((v.u >> 16) & 1u);
    return (ushort_t)(r >> 16);
}

// ---------------------------------------------------------------------------
// fp32 -> bf16 tensor conversion (weights, once per launch)
// ---------------------------------------------------------------------------
__global__ __launch_bounds__(256) void f2b_kernel(const float* __restrict__ src,
                                                  ushort_t* __restrict__ dst, int n4) {
    int i = blockIdx.x * 256 + threadIdx.x;
    if (i < n4) {
        float4 v = ((const float4*)src)[i];
        uint2 pk;
        pk.x = (unsigned)bf16_rn(v.x) | ((unsigned)bf16_rn(v.y) << 16);
        pk.y = (unsigned)bf16_rn(v.z) | ((unsigned)bf16_rn(v.w) << 16);
        ((uint2*)dst)[i] = pk;
    }
}

// ---------------------------------------------------------------------------
// LayerNorm: one wave per row of 512, bf16 output (feeds a GEMM)
// ---------------------------------------------------------------------------
__global__ __launch_bounds__(64) void ln_kernel(const float* __restrict__ x,
                                                const float* __restrict__ g,
                                                const float* __restrict__ b,
                                                ushort_t* __restrict__ out) {
    int row = blockIdx.x;
    int lane = threadIdx.x;
    const float* xr = x + (size_t)row * D_MODEL;
    float4 v0 = *(const float4*)(xr + lane * 8);
    float4 v1 = *(const float4*)(xr + lane * 8 + 4);
    float s = v0.x + v0.y + v0.z + v0.w + v1.x + v1.y + v1.z + v1.w;
    float ss = v0.x * v0.x + v0.y * v0.y + v0.z * v0.z + v0.w * v0.w +
               v1.x * v1.x + v1.y * v1.y + v1.z * v1.z + v1.w * v1.w;
#pragma unroll
    for (int o = 32; o >= 1; o >>= 1) {
        s += __shfl_xor(s, o);
        ss += __shfl_xor(ss, o);
    }
    float mean = s * (1.f / D_MODEL);
    float var = ss * (1.f / D_MODEL) - mean * mean;
    float rstd = rsqrtf(var + 1e-5f);
    float4 g0 = *(const float4*)(g + lane * 8);
    float4 g1 = *(const float4*)(g + lane * 8 + 4);
    float4 b0 = *(const float4*)(b + lane * 8);
    float4 b1 = *(const float4*)(b + lane * 8 + 4);
    float o0 = (v0.x - mean) * rstd * g0.x + b0.x;
    float o1 = (v0.y - mean) * rstd * g0.y + b0.y;
    float o2 = (v0.z - mean) * rstd * g0.z + b0.z;
    float o3 = (v0.w - mean) * rstd * g0.w + b0.w;
    float o4 = (v1.x - mean) * rstd * g1.x + b1.x;
    float o5 = (v1.y - mean) * rstd * g1.y + b1.y;
    float o6 = (v1.z - mean) * rstd * g1.z + b1.z;
    float o7 = (v1.w - mean) * rstd * g1.w + b1.w;
    uint4 pk;
    pk.x = (unsigned)bf16_rn(o0) | ((unsigned)bf16_rn(o1) << 16);
    pk.y = (unsigned)bf16_rn(o2) | ((unsigned)bf16_rn(o3) << 16);
    pk.z = (unsigned)bf16_rn(o4) | ((unsigned)bf16_rn(o5) << 16);
    pk.w = (unsigned)bf16_rn(o6) | ((unsigned)bf16_rn(o7) << 16);
    *(uint4*)(out + (size_t)row * D_MODEL + lane * 8) = pk;
}

// ---------------------------------------------------------------------------
// bf16 MFMA GEMM: C[m,n] = epi( sum_k A[m,k]*W[n,k] ), fp32 accumulate.
// A [M,K] bf16 row-major, W [N,K] bf16 row-major. 256 threads = 2x2 waves.
// EPI: 0 fp32  1 bias+softplus fp32  2 +res fp32  3 bias+gelu -> bf16
//      4 bias+res fp32  5 fp32 + bf16 compact copy of cols<32 (dtr)
// ---------------------------------------------------------------------------
template <int BMt, int BNt, int EPI>
__global__ __launch_bounds__(256) void bgemm_kernel(
    const ushort_t* __restrict__ A, const ushort_t* __restrict__ W,
    const float* __restrict__ bias, const float* __restrict__ res,
    float* __restrict__ C, ushort_t* __restrict__ Cb,
    int M, int N, int K) {
    constexpr int WM = BMt / 2, WN = BNt / 2;
    constexpr int MT = WM / 16, NT = WN / 16;
    constexpr int ACH = BMt * 4;            // 16B chunks in A tile
    constexpr int TOT = ACH + BNt * 4;
    constexpr int NIT = TOT / 256;
    __shared__ ushort_t As[BMt * 32];
    __shared__ ushort_t Ws[BNt * 32];

    int tid = threadIdx.x;
    int lane = tid & 63;
    int wv = tid >> 6;
    int wrow = wv >> 1, wcol = wv & 1;
    int m0 = blockIdx.y * BMt, n0 = blockIdx.x * BNt;
    int lrow = lane & 15;
    int ko = lane >> 4;

    f32x4 acc[MT][NT] = {};

    for (int k0 = 0; k0 < K; k0 += 32) {
#pragma unroll
        for (int i = 0; i < NIT; i++) {
            int e = tid + i * 256;
            const ushort_t* gp;
            ushort_t* lp;
            if (e < ACH) {
                int row = e >> 2, ch = e & 3;
                gp = A + (size_t)(m0 + row) * K + k0 + ch * 8;
                lp = As + e * 8;
            } else {
                int e2 = e - ACH;
                int row = e2 >> 2, ch = e2 & 3;
                gp = W + (size_t)(n0 + row) * K + k0 + ch * 8;
                lp = Ws + e2 * 8;
            }
            __builtin_amdgcn_global_load_lds(
                (const __attribute__((address_space(1))) void*)gp,
                (__attribute__((address_space(3))) void*)lp, 16, 0, 0);
        }
        __syncthreads();
        short8 a[MT], b[NT];
#pragma unroll
        for (int mt = 0; mt < MT; mt++) {
            int ml = wrow * WM + mt * 16 + lrow;
            a[mt] = *(const short8*)(As + ml * 32 + ko * 8);
        }
#pragma unroll
        for (int nt = 0; nt < NT; nt++) {
            int nl = wcol * WN + nt * 16 + lrow;
            b[nt] = *(const short8*)(Ws + nl * 32 + ko * 8);
        }
#pragma unroll
        for (int mt = 0; mt < MT; mt++)
#pragma unroll
            for (int nt = 0; nt < NT; nt++)
                acc[mt][nt] = __builtin_amdgcn_mfma_f32_16x16x32_bf16(
                    a[mt], b[nt], acc[mt][nt], 0, 0, 0);
        __syncthreads();
    }

    int r4 = lane >> 4;
#pragma unroll
    for (int mt = 0; mt < MT; mt++) {
#pragma unroll
        for (int nt = 0; nt < NT; nt++) {
            int n = n0 + wcol * WN + nt * 16 + lrow;
#pragma unroll
            for (int i = 0; i < 4; i++) {
                int m = m0 + wrow * WM + mt * 16 + r4 * 4 + i;
                float v = acc[mt][nt][i];
                size_t off = (size_t)m * N + n;
                if (EPI == 0) {
                    C[off] = v;
                } else if (EPI == 1) {
                    float t = v + bias[n];
                    C[off] = (t > 20.f) ? t : log1pf(expf(t));
                } else if (EPI == 2) {
                    C[off] = v + res[off];
                } else if (EPI == 3) {
                    float t = v + bias[n];
                    Cb[off] = bf16_rn(0.5f * t * (1.f + erff(t * 0.70710678118654752f)));
                } else if (EPI == 4) {
                    C[off] = v + bias[n] + res[off];
                } else if (EPI == 5) {
                    C[off] = v;
                    if (n < DT_RANK) Cb[(size_t)m * DT_RANK + n] = bf16_rn(v);
                }
            }
        }
    }
}

// ---------------------------------------------------------------------------
// Causal depthwise conv (width 4) + bias + SiLU; dual fp32/bf16 output.
// ---------------------------------------------------------------------------
__global__ __launch_bounds__(256) void conv_silu_kernel(
    const float* __restrict__ xz, const float* __restrict__ cw,
    const float* __restrict__ cb, float* __restrict__ xc_f,
    ushort_t* __restrict__ xc_b) {
    int idx = blockIdx.x * 256 + threadIdx.x;  // 0 .. 4M-1
    int d = idx & (D_INNER - 1);
    int t = (idx >> 10) & (L_SEQ - 1);
    int b = idx >> 20;
    float acc = cb[d];
    const float* base = xz + (size_t)(b * L_SEQ) * (2 * D_INNER) + d;
#pragma unroll
    for (int j = 0; j < 4; j++) {
        int tt = t - 3 + j;
        if (tt >= 0) acc += cw[d * 4 + j] * base[(size_t)tt * (2 * D_INNER)];
    }
    float s = __fdividef(acc, 1.f + __expf(-acc));
    xc_f[idx] = s;
    xc_b[idx] = bf16_rn(s);
}

// ---------------------------------------------------------------------------
// Chunked selective scan, d-per-lane layout: one lane per (b,chunk,d), all 16
// states in registers. B/C rows are wave-uniform -> scalar loads. No cross-
// lane reduce. pass2 composes the 32 chunks and stores Hin in-place in Pbuf.
// ---------------------------------------------------------------------------
__global__ __launch_bounds__(256) void scan_pass1(
    const float* __restrict__ dt, const float* __restrict__ xc,
    const float* __restrict__ dbl, const float* __restrict__ A_log,
    float* __restrict__ Pbuf, float* __restrict__ Sbuf) {
    int tid = threadIdx.x;
    int blk = blockIdx.x;            // b*(NCHUNK*4) + c*4 + dg
    int dg = blk & 3;
    int c = (blk >> 2) & (NCHUNK - 1);
    int b = blk >> 7;
    int d = dg * 256 + tid;

    float A2[16], h[16], P[16];
    const float* ar = A_log + d * 16;
#pragma unroll
    for (int s = 0; s < 16; s++) {
        A2[s] = -__expf(ar[s]);
        h[s] = 0.f;
        P[s] = 1.f;
    }
    size_t rbase = (size_t)b * L_SEQ + (size_t)c * CHUNK;
    const float* dtp = dt + rbase * D_INNER + d;
    const float* xcp = xc + rbase * D_INNER + d;
    const float* blp = dbl + rbase * 64 + DT_RANK;   // B row (wave-uniform)

    float dtv = dtp[0];
    float xcv = xcp[0];
    float Ba[16], Bb[16];
#pragma unroll
    for (int s = 0; s < 16; s++) Ba[s] = blp[s];

    for (int t = 0; t < CHUNK; t += 2) {
        // prefetch t+1 (CHUNK even -> always valid)
        float dt1 = dtp[(size_t)(t + 1) * D_INNER];
        float xc1 = xcp[(size_t)(t + 1) * D_INNER];
#pragma unroll
        for (int s = 0; s < 16; s++) Bb[s] = blp[(t + 1) * 64 + s];
        {
            float u = dtv * xcv;
#pragma unroll
            for (int s = 0; s < 16; s++) {
                float a = __expf(dtv * A2[s]);
                h[s] = a * h[s] + u * Ba[s];
                P[s] *= a;
            }
        }
        // prefetch t+2
        float dt2 = 0.f, xc2 = 0.f;
        if (t + 2 < CHUNK) {
            dt2 = dtp[(size_t)(t + 2) * D_INNER];
            xc2 = xcp[(size_t)(t + 2) * D_INNER];
#pragma unroll
            for (int s = 0; s < 16; s++) Ba[s] = blp[(t + 2) * 64 + s];
        }
        {
            float u = dt1 * xc1;
#pragma unroll
            for (int s = 0; s < 16; s++) {
                float a = __expf(dt1 * A2[s]);
                h[s] = a * h[s] + u * Bb[s];
                P[s] *= a;
            }
        }
        dtv = dt2; xcv = xc2;
    }
    float* Pp = Pbuf + (((size_t)b * NCHUNK + c) * D_INNER + d) * 16;
    float* Sp = Sbuf + (((size_t)b * NCHUNK + c) * D_INNER + d) * 16;
#pragma unroll
    for (int q = 0; q < 4; q++) {
        *(float4*)(Pp + 4 * q) = make_float4(P[4 * q], P[4 * q + 1], P[4 * q + 2], P[4 * q + 3]);
        *(float4*)(Sp + 4 * q) = make_float4(h[4 * q], h[4 * q + 1], h[4 * q + 2], h[4 * q + 3]);
    }
}

// composes chunks; overwrites Pbuf[o] with Hin (incoming state) for chunk c.
// Each thread owns one (b,d,s) slice across all chunks -> no hazards.
__global__ __launch_bounds__(256) void scan_pass2(
    float* __restrict__ Pbuf, const float* __restrict__ Sbuf) {
    int idx = blockIdx.x * 256 + threadIdx.x;  // over B*D_INNER*D_STATE
    int sd = idx & 16383;
    int b = idx >> 14;
    float H = 0.f;
#pragma unroll
    for (int c = 0; c < NCHUNK; c++) {
        size_t o = ((size_t)(b * NCHUNK + c) << 14) + sd;
        float Pv = Pbuf[o];
        float Sv = Sbuf[o];
        Pbuf[o] = H;
        H = Pv * H + Sv;
    }
}

__global__ __launch_bounds__(256) void scan_pass3(
    const float* __restrict__ dt, const float* __restrict__ xc,
    const float* __restrict__ dbl, const float* __restrict__ xz,
    const float* __restrict__ A_log, const float* __restrict__ Dsk,
    const float* __restrict__ Hin, ushort_t* __restrict__ y) {
    int tid = threadIdx.x;
    int blk = blockIdx.x;
    int dg = blk & 3;
    int c = (blk >> 2) & (NCHUNK - 1);
    int b = blk >> 7;
    int d = dg * 256 + tid;

    float A2[16], h[16];
    const float* ar = A_log + d * 16;
#pragma unroll
    for (int s = 0; s < 16; s++) A2[s] = -__expf(ar[s]);
    float Dv = Dsk[d];
    const float* Hp = Hin + (((size_t)b * NCHUNK + c) * D_INNER + d) * 16;
#pragma unroll
    for (int q = 0; q < 4; q++) {
        float4 hv = *(const float4*)(Hp + 4 * q);
        h[4 * q] = hv.x; h[4 * q + 1] = hv.y; h[4 * q + 2] = hv.z; h[4 * q + 3] = hv.w;
    }

    size_t rbase = (size_t)b * L_SEQ + (size_t)c * CHUNK;
    const float* dtp = dt + rbase * D_INNER + d;
    const float* xcp = xc + rbase * D_INNER + d;
    const float* blp = dbl + rbase * 64 + DT_RANK;   // [B(16) | C(16)] wave-uniform
    const float* zp = xz + rbase * (2 * D_INNER) + D_INNER + d;
    ushort_t* yp = y + rbase * D_INNER + d;

    float dtv = dtp[0];
    float xcv = xcp[0];
    float zv = zp[0];
    float BCa[32], BCb[32];
#pragma unroll
    for (int s = 0; s < 32; s++) BCa[s] = blp[s];

    for (int t = 0; t < CHUNK; t += 2) {
        float dt1 = dtp[(size_t)(t + 1) * D_INNER];
        float xc1 = xcp[(size_t)(t + 1) * D_INNER];
        float z1 = zp[(size_t)(t + 1) * (2 * D_INNER)];
#pragma unroll
        for (int s = 0; s < 32; s++) BCb[s] = blp[(t + 1) * 64 + s];
        {
            float u = dtv * xcv;
            float p = Dv * xcv;
#pragma unroll
            for (int s = 0; s < 16; s++) {
                float a = __expf(dtv * A2[s]);
                h[s] = a * h[s] + u * BCa[s];
                p = fmaf(h[s], BCa[16 + s], p);
            }
            float sig = __fdividef(zv, 1.f + __expf(-zv));
            yp[(size_t)t * D_INNER] = bf16_rn(p * sig);
        }
        float dt2 = 0.f, xc2 = 0.f, z2 = 0.f;
        if (t + 2 < CHUNK) {
            dt2 = dtp[(size_t)(t + 2) * D_INNER];
            xc2 = xcp[(size_t)(t + 2) * D_INNER];
            z2 = zp[(size_t)(t + 2) * (2 * D_INNER)];
#pragma unroll
            for (int s = 0; s < 32; s++) BCa[s] = blp[(t + 2) * 64 + s];
        }
        {
            float u = dt1 * xc1;
            float p = Dv * xc1;
#pragma unroll
            for (int s = 0; s < 16; s++) {
                float a = __expf(dt1 * A2[s]);
                h[s] = a * h[s] + u * BCb[s];
                p = fmaf(h[s], BCb[16 + s], p);
            }
            float sig = __fdividef(z1, 1.f + __expf(-z1));
            yp[(size_t)(t + 1) * D_INNER] = bf16_rn(p * sig);
        }
        dtv = dt2; xcv = xc2; zv = z2;
    }
}

// ---------------------------------------------------------------------------
// Host launcher
// ---------------------------------------------------------------------------
extern "C" void kernel_launch(void* const* d_in, const int* in_sizes, int n_in,
                              void* d_out, int out_size, void* d_ws, size_t ws_size,
                              hipStream_t stream) {
    const float* x_in     = (const float*)d_in[0];
    const float* ln1_g    = (const float*)d_in[1];
    const float* ln1_b    = (const float*)d_in[2];
    const float* in_w     = (const float*)d_in[3];
    const float* conv_w   = (const float*)d_in[4];
    const float* conv_b   = (const float*)d_in[5];
    const float* xproj_w  = (const float*)d_in[6];
    const float* dtproj_w = (const float*)d_in[7];
    const float* dtproj_b = (const float*)d_in[8];
    const float* A_log    = (const float*)d_in[9];
    const float* D_skip   = (const float*)d_in[10];
    const float* out_w    = (const float*)d_in[11];
    const float* ln2_g    = (const float*)d_in[12];
    const float* ln2_b    = (const float*)d_in[13];
    const float* mlp_w1   = (const float*)d_in[14];
    const float* mlp_b1   = (const float*)d_in[15];
    const float* mlp_w2   = (const float*)d_in[16];
    const float* mlp_b2   = (const float*)d_in[17];

    char* p = (char*)d_ws;
    float* x_buf = (float*)p;        p += (size_t)NROWS * 512 * 4;
    float* xz    = (float*)p;        p += (size_t)NROWS * 2048 * 4;
    float* xc_f  = (float*)p;        p += (size_t)NROWS * 1024 * 4;
    float* dbl   = (float*)p;        p += (size_t)NROWS * 64 * 4;
    float* dt    = (float*)p;        p += (size_t)NROWS * 1024 * 4;
    float* Pbuf  = (float*)p;        p += (size_t)BSZ * NCHUNK * 16384 * 4;  // 8 MB
    float* Sbuf  = (float*)p;        p += (size_t)BSZ * NCHUNK * 16384 * 4;  // 8 MB
    ushort_t* xn_b  = (ushort_t*)p;  p += (size_t)NROWS * 512 * 2;
    ushort_t* xc_b  = (ushort_t*)p;  p += (size_t)NROWS * 1024 * 2;
    ushort_t* dtr_b = (ushort_t*)p;  p += (size_t)NROWS * 32 * 2;
    ushort_t* yc_b  = (ushort_t*)p;  p += (size_t)NROWS * 1024 * 2;
    ushort_t* wi_b  = (ushort_t*)p;  p += (size_t)5 * 2048 * 512 * 2;
    ushort_t* wx_b  = (ushort_t*)p;  p += (size_t)5 * 64 * 1024 * 2;
    ushort_t* wd_b  = (ushort_t*)p;  p += (size_t)5 * 1024 * 32 * 2;
    ushort_t* wo_b  = (ushort_t*)p;  p += (size_t)5 * 512 * 1024 * 2;
    ushort_t* w1_b  = (ushort_t*)p;  p += (size_t)5 * 1024 * 512 * 2;
    ushort_t* w2_b  = (ushort_t*)p;  p += (size_t)5 * 512 * 1024 * 2;
    ushort_t* h1_b  = (ushort_t*)xz; // alias: xz is dead once mlp1 runs

    // weight conversion (every launch; inputs are re-restored by harness)
    f2b_kernel<<<(5 * 2048 * 512 / 4 + 255) / 256, 256, 0, stream>>>(in_w, wi_b, 5 * 2048 * 512 / 4);
    f2b_kernel<<<(5 * 64 * 1024 / 4 + 255) / 256, 256, 0, stream>>>(xproj_w, wx_b, 5 * 64 * 1024 / 4);
    f2b_kernel<<<(5 * 1024 * 32 / 4 + 255) / 256, 256, 0, stream>>>(dtproj_w, wd_b, 5 * 1024 * 32 / 4);
    f2b_kernel<<<(5 * 512 * 1024 / 4 + 255) / 256, 256, 0, stream>>>(out_w, wo_b, 5 * 512 * 1024 / 4);
    f2b_kernel<<<(5 * 1024 * 512 / 4 + 255) / 256, 256, 0, stream>>>(mlp_w1, w1_b, 5 * 1024 * 512 / 4);
    f2b_kernel<<<(5 * 512 * 1024 / 4 + 255) / 256, 256, 0, stream>>>(mlp_w2, w2_b, 5 * 512 * 1024 / 4);

    for (int d = 0; d < 5; d++) {
        const float* xsrc = (d == 0) ? x_in : x_buf;

        // LN1 -> bf16
        ln_kernel<<<NROWS, 64, 0, stream>>>(xsrc, ln1_g + d * 512, ln1_b + d * 512, xn_b);
        // in_proj: 4096x2048, K=512
        bgemm_kernel<128, 128, 0><<<dim3(16, 32), 256, 0, stream>>>(
            xn_b, wi_b + (size_t)d * 2048 * 512, nullptr, nullptr, xz, nullptr,
            NROWS, 2048, 512);
        // conv + silu
        conv_silu_kernel<<<(NROWS * D_INNER) / 256, 256, 0, stream>>>(
            xz, conv_w + d * 4096, conv_b + d * 1024, xc_f, xc_b);
        // xproj: 4096x64, K=1024 -> dbl fp32 + dtr bf16
        bgemm_kernel<64, 64, 5><<<dim3(1, 64), 256, 0, stream>>>(
            xc_b, wx_b + (size_t)d * 64 * 1024, nullptr, nullptr, dbl, dtr_b,
            NROWS, 64, 1024);
        // dtproj + softplus: 4096x1024, K=32
        bgemm_kernel<128, 128, 1><<<dim3(8, 32), 256, 0, stream>>>(
            dtr_b, wd_b + (size_t)d * 1024 * 32, dtproj_b + d * 1024, nullptr, dt, nullptr,
            NROWS, 1024, 32);
        // chunked scan (d-per-lane)
        scan_pass1<<<BSZ * NCHUNK * 4, 256, 0, stream>>>(
            dt, xc_f, dbl, A_log + d * 16384, Pbuf, Sbuf);
        scan_pass2<<<(BSZ * D_INNER * D_STATE) / 256, 256, 0, stream>>>(Pbuf, Sbuf);
        scan_pass3<<<BSZ * NCHUNK * 4, 256, 0, stream>>>(
            dt, xc_f, dbl, xz, A_log + d * 16384, D_skip + d * 1024, Pbuf, yc_b);
        // out_proj + residual: 4096x512, K=1024
        bgemm_kernel<128, 64, 2><<<dim3(8, 32), 256, 0, stream>>>(
            yc_b, wo_b + (size_t)d * 512 * 1024, nullptr, xsrc, x_buf, nullptr,
            NROWS, 512, 1024);
        // LN2 -> bf16
        ln_kernel<<<NROWS, 64, 0, stream>>>(x_buf, ln2_g + d * 512, ln2_b + d * 512, xn_b);
        // mlp1 + bias + gelu -> bf16 h1: 4096x1024, K=512
        bgemm_kernel<128, 128, 3><<<dim3(8, 32), 256, 0, stream>>>(
            xn_b, w1_b + (size_t)d * 1024 * 512, mlp_b1 + d * 1024, nullptr, nullptr, h1_b,
            NROWS, 1024, 512);
        // mlp2 + bias + residual: 4096x512, K=1024
        float* dst = (d == 4) ? (float*)d_out : x_buf;
        bgemm_kernel<128, 64, 4><<<dim3(8, 32), 256, 0, stream>>>(
            h1_b, w2_b + (size_t)d * 512 * 1024, mlp_b2 + d * 512, x_buf, dst, nullptr,
            NROWS, 512, 1024);
    }
}